// Round 1
// baseline (7805.337 us; speedup 1.0000x reference)
//
#include <hip/hip_runtime.h>

#define NCH 128
#define NREL 64
#define NBASES 8

// ---------------- W[r] = sum_b att[r,b] * basis[b] ----------------
__global__ __launch_bounds__(256) void k_buildW(const float* __restrict__ basis,
                                                const float* __restrict__ att,
                                                float* __restrict__ W) {
    int r = blockIdx.x;
    float a[NBASES];
#pragma unroll
    for (int b = 0; b < NBASES; ++b) a[b] = att[r * NBASES + b];
    const float4* b4 = (const float4*)basis;             // 8 * 4096 float4
    float4* w4 = (float4*)(W + (size_t)r * NCH * NCH);   // 4096 float4
    for (int i = threadIdx.x; i < NCH * NCH / 4; i += blockDim.x) {
        float4 s = make_float4(0.f, 0.f, 0.f, 0.f);
#pragma unroll
        for (int b = 0; b < NBASES; ++b) {
            float4 v = b4[(size_t)b * (NCH * NCH / 4) + i];
            s.x += a[b] * v.x; s.y += a[b] * v.y;
            s.z += a[b] * v.z; s.w += a[b] * v.w;
        }
        w4[i] = s;
    }
}

// ---------------- histogram: deg[dst]++, hist[rel]++ ----------------
__global__ __launch_bounds__(256) void k_count(const int* __restrict__ triples, int E,
                                               int* __restrict__ deg, int* __restrict__ hist) {
    int e = blockIdx.x * blockDim.x + threadIdx.x;
    if (e < E) {
        int rel = triples[3 * e + 1];
        int dst = triples[3 * e + 2];
        atomicAdd(&deg[dst], 1);
        atomicAdd(&hist[rel], 1);
    }
}

// ---------------- tiny exclusive scan over 64 relations ----------------
__global__ void k_scan(const int* __restrict__ hist, int* __restrict__ edge_off,
                       int* __restrict__ tile_off, int* __restrict__ cursor) {
    if (threadIdx.x == 0 && blockIdx.x == 0) {
        int es = 0, ts = 0;
        for (int r = 0; r < NREL; ++r) {
            edge_off[r] = es; tile_off[r] = ts; cursor[r] = es;
            es += hist[r];
            ts += (hist[r] + 63) >> 6;
        }
        edge_off[NREL] = es; tile_off[NREL] = ts;
    }
}

// ---------------- counting sort: perm grouped by rel ----------------
__global__ __launch_bounds__(256) void k_scatter(const int* __restrict__ triples, int E,
                                                 int* __restrict__ cursor, int* __restrict__ perm) {
    int e = blockIdx.x * blockDim.x + threadIdx.x;
    if (e < E) {
        int rel = triples[3 * e + 1];
        int pos = atomicAdd(&cursor[rel], 1);
        perm[pos] = e;
    }
}

// ---------------- main: per (rel, 64-edge tile) GEMM + atomic scatter ----------------
__global__ __launch_bounds__(256) void k_msgs(const float* __restrict__ x,
                                              const int* __restrict__ triples,
                                              const float* __restrict__ W,
                                              const int* __restrict__ deg,
                                              const int* __restrict__ edge_off,
                                              const int* __restrict__ tile_off,
                                              const int* __restrict__ perm,
                                              float* __restrict__ out) {
    __shared__ float Xg[64][NCH];
    __shared__ int sdst[64];

    int b = blockIdx.x;
    if (b >= tile_off[NREL]) return;
    int r = 0;
#pragma unroll 1
    for (; r < NREL; ++r) { if (b < tile_off[r + 1]) break; }
    int tile = b - tile_off[r];
    int estart = edge_off[r] + tile * 64;
    int count = min(64, edge_off[r + 1] - estart);

    int t = threadIdx.x;
    int row = t >> 2, part = t & 3;  // 4 threads per edge row
    if (row < count) {
        int e = perm[estart + row];
        int src = triples[3 * e];
        int dst = triples[3 * e + 2];
        float scale = 1.0f / (float)deg[dst];
        if (part == 0) sdst[row] = dst;
        const float4* xr = (const float4*)(x + (size_t)src * NCH);
        float4* xg = (float4*)(&Xg[row][0]);
#pragma unroll
        for (int j = 0; j < 8; ++j) {
            float4 v = xr[part * 8 + j];
            v.x *= scale; v.y *= scale; v.z *= scale; v.w *= scale;
            xg[part * 8 + j] = v;
        }
    }
    __syncthreads();

    // register tile: 8 edges x 4 out-channels per thread
    int oc = (t & 31) * 4;   // 0..124
    int eg = t >> 5;         // 0..7
    const float* Wr = W + (size_t)r * NCH * NCH;  // layout [ic][oc]
    float acc[8][4];
#pragma unroll
    for (int i = 0; i < 8; ++i)
#pragma unroll
        for (int j = 0; j < 4; ++j) acc[i][j] = 0.f;

    for (int ic = 0; ic < NCH; ic += 4) {
        float4 w0 = *(const float4*)(Wr + (size_t)(ic + 0) * NCH + oc);
        float4 w1 = *(const float4*)(Wr + (size_t)(ic + 1) * NCH + oc);
        float4 w2 = *(const float4*)(Wr + (size_t)(ic + 2) * NCH + oc);
        float4 w3 = *(const float4*)(Wr + (size_t)(ic + 3) * NCH + oc);
#pragma unroll
        for (int i = 0; i < 8; ++i) {
            float4 xv = *(const float4*)(&Xg[eg * 8 + i][ic]);
            acc[i][0] += xv.x * w0.x + xv.y * w1.x + xv.z * w2.x + xv.w * w3.x;
            acc[i][1] += xv.x * w0.y + xv.y * w1.y + xv.z * w2.y + xv.w * w3.y;
            acc[i][2] += xv.x * w0.z + xv.y * w1.z + xv.z * w2.z + xv.w * w3.z;
            acc[i][3] += xv.x * w0.w + xv.y * w1.w + xv.z * w2.w + xv.w * w3.w;
        }
    }

#pragma unroll
    for (int i = 0; i < 8; ++i) {
        int rrow = eg * 8 + i;
        if (rrow < count) {
            float* op = out + (size_t)sdst[rrow] * NCH + oc;
            atomicAdd(op + 0, acc[i][0]);
            atomicAdd(op + 1, acc[i][1]);
            atomicAdd(op + 2, acc[i][2]);
            atomicAdd(op + 3, acc[i][3]);
        }
    }
}

// ---------------- epilogue: out += x @ root_w + root_b ----------------
__global__ __launch_bounds__(256) void k_root(const float* __restrict__ x,
                                              const float* __restrict__ rw,
                                              const float* __restrict__ rb,
                                              float* __restrict__ out, int N) {
    __shared__ float Xs[8][NCH];
    int n0 = blockIdx.x * 8;
    int t = threadIdx.x;
    {
        int rown = t >> 5, c4 = t & 31;  // one float4 per thread
        int n = n0 + rown;
        float4 v = make_float4(0.f, 0.f, 0.f, 0.f);
        if (n < N) v = ((const float4*)x)[(size_t)n * (NCH / 4) + c4];
        ((float4*)&Xs[rown][0])[c4] = v;
    }
    __syncthreads();
    int oc = (t & 31) * 4;
    int ng = t >> 5;
    int n = n0 + ng;
    if (n >= N) return;
    float a0 = rb[oc], a1 = rb[oc + 1], a2 = rb[oc + 2], a3 = rb[oc + 3];
    for (int ic = 0; ic < NCH; ++ic) {
        float xs = Xs[ng][ic];
        float4 w = *(const float4*)(rw + (size_t)ic * NCH + oc);
        a0 += xs * w.x; a1 += xs * w.y; a2 += xs * w.z; a3 += xs * w.w;
    }
    float* op = out + (size_t)n * NCH + oc;
    op[0] += a0; op[1] += a1; op[2] += a2; op[3] += a3;
}

extern "C" void kernel_launch(void* const* d_in, const int* in_sizes, int n_in,
                              void* d_out, int out_size, void* d_ws, size_t ws_size,
                              hipStream_t stream) {
    const float* x   = (const float*)d_in[0];
    const int* trip  = (const int*)d_in[1];
    const float* basis = (const float*)d_in[3];
    const float* att   = (const float*)d_in[4];
    const float* rw    = (const float*)d_in[5];
    const float* rb    = (const float*)d_in[6];
    float* out = (float*)d_out;

    int N = in_sizes[0] / NCH;
    int E = in_sizes[1] / 3;

    char* ws = (char*)d_ws;
    size_t off = 0;
    auto alloc = [&](size_t bytes) { size_t o = off; off = (off + bytes + 255) & ~(size_t)255; return o; };
    size_t offW    = alloc((size_t)NREL * NCH * NCH * 4);  // 4 MB
    size_t offDeg  = alloc((size_t)N * 4);
    size_t offHist = alloc(NREL * 4);
    size_t offEOff = alloc((NREL + 1) * 4);
    size_t offTOff = alloc((NREL + 1) * 4);
    size_t offCur  = alloc(NREL * 4);
    size_t offPerm = alloc((size_t)E * 4);
    (void)ws_size;

    float* W      = (float*)(ws + offW);
    int* deg      = (int*)(ws + offDeg);
    int* hist     = (int*)(ws + offHist);
    int* edge_off = (int*)(ws + offEOff);
    int* tile_off = (int*)(ws + offTOff);
    int* cursor   = (int*)(ws + offCur);
    int* perm     = (int*)(ws + offPerm);

    // zero: out accumulator + deg..hist region
    hipMemsetAsync(out, 0, (size_t)out_size * 4, stream);
    hipMemsetAsync(ws + offDeg, 0, offEOff - offDeg, stream);

    k_buildW<<<NREL, 256, 0, stream>>>(basis, att, W);
    k_count<<<(E + 255) / 256, 256, 0, stream>>>(trip, E, deg, hist);
    k_scan<<<1, 1, 0, stream>>>(hist, edge_off, tile_off, cursor);
    k_scatter<<<(E + 255) / 256, 256, 0, stream>>>(trip, E, cursor, perm);

    int nTiles = (E + 63) / 64 + NREL;  // upper bound on total tiles
    k_msgs<<<nTiles, 256, 0, stream>>>(x, trip, W, deg, edge_off, tile_off, perm, out);

    k_root<<<(N + 7) / 8, 256, 0, stream>>>(x, rw, rb, out, N);
}

// Round 2
// 912.509 us; speedup vs baseline: 8.5537x; 8.5537x over previous
//
#include <hip/hip_runtime.h>

#define NCH 128
#define NREL 64
#define MAXC 16
#define MAXK (NREL * MAXC)  // 1024

typedef __attribute__((ext_vector_type(8))) short bf16x8;
typedef __attribute__((ext_vector_type(4))) float f32x4;

__device__ __forceinline__ unsigned short f2bf(float f) {
    unsigned u = __float_as_uint(f);
    return (unsigned short)((u + 0x7fffu + ((u >> 16) & 1u)) >> 16);  // RNE
}

// ---------------- Wbt[r][oc][ic] bf16 = (sum_b att*basis)^T ; rwbt[oc][ic] ----------------
__global__ __launch_bounds__(256) void k_buildW(const float* __restrict__ basis,
                                                const float* __restrict__ att,
                                                const float* __restrict__ rw,
                                                unsigned short* __restrict__ Wbt,
                                                unsigned short* __restrict__ rwbt) {
    int r = blockIdx.x, t = threadIdx.x;
    if (r < NREL) {
        float a[8];
#pragma unroll
        for (int b = 0; b < 8; ++b) a[b] = att[r * 8 + b];
        for (int idx = t; idx < NCH * NCH; idx += 256) {
            int ic = idx >> 7, oc = idx & 127;
            float s = 0.f;
#pragma unroll
            for (int b = 0; b < 8; ++b) s += a[b] * basis[b * NCH * NCH + ic * NCH + oc];
            Wbt[(size_t)r * NCH * NCH + oc * NCH + ic] = f2bf(s);
        }
    } else {
        for (int idx = t; idx < NCH * NCH; idx += 256) {
            int ic = idx >> 7, oc = idx & 127;
            rwbt[oc * NCH + ic] = f2bf(rw[ic * NCH + oc]);
        }
    }
}

// ---------------- deg[dst]++, hist[key]++ (LDS-aggregated), key = chunk(dst)*64+rel --------
__global__ __launch_bounds__(256) void k_count(const int* __restrict__ trip, int E,
                                               int chunkNodes, int NK,
                                               int* __restrict__ deg, int* __restrict__ hist) {
    __shared__ int h[MAXK];
    int t = threadIdx.x;
    for (int k = t; k < NK; k += 256) h[k] = 0;
    __syncthreads();
    int base = blockIdx.x * 4096;
#pragma unroll 4
    for (int i = 0; i < 16; ++i) {
        int e = base + i * 256 + t;
        if (e < E) {
            int rel = trip[3 * e + 1], dst = trip[3 * e + 2];
            atomicAdd(&h[(dst / chunkNodes) * NREL + rel], 1);
            atomicAdd(&deg[dst], 1);
        }
    }
    __syncthreads();
    for (int k = t; k < NK; k += 256) {
        int v = h[k];
        if (v) atomicAdd(&hist[k], v);
    }
}

// ---------------- scan over NK keys: keyoff/tileoff/cursor_key ----------------
__global__ __launch_bounds__(1024) void k_scan_keys(const int* __restrict__ hist, int NK,
                                                    int* __restrict__ keyoff,
                                                    int* __restrict__ tileoff,
                                                    int* __restrict__ cursor_key) {
    __shared__ int sc[1024], st[1024];
    int t = threadIdx.x;
    int c = (t < NK) ? hist[t] : 0;
    int tl = (c + 63) >> 6;
    sc[t] = c; st[t] = tl;
    __syncthreads();
    for (int off = 1; off < 1024; off <<= 1) {
        int a = 0, b = 0;
        if (t >= off) { a = sc[t - off]; b = st[t - off]; }
        __syncthreads();
        sc[t] += a; st[t] += b;
        __syncthreads();
    }
    if (t < NK) { keyoff[t] = sc[t] - c; tileoff[t] = st[t] - tl; cursor_key[t] = sc[t] - c; }
    if (t == NK - 1) { keyoff[NK] = sc[t]; tileoff[NK] = st[t]; }
}

// ---------------- 3-kernel scan over N (dstoff = exclusive scan of deg) ----------------
__global__ __launch_bounds__(1024) void k_scan_blk(const int* __restrict__ deg, int N,
                                                   int* __restrict__ dstoff, int* __restrict__ bsum) {
    __shared__ int sc[1024];
    int t = threadIdx.x, i = blockIdx.x * 1024 + t;
    int v = (i < N) ? deg[i] : 0;
    sc[t] = v;
    __syncthreads();
    for (int off = 1; off < 1024; off <<= 1) {
        int a = 0;
        if (t >= off) a = sc[t - off];
        __syncthreads();
        sc[t] += a;
        __syncthreads();
    }
    if (i < N) dstoff[i + 1] = sc[t];
    if (t == 1023) bsum[blockIdx.x] = sc[1023];
}
__global__ __launch_bounds__(1024) void k_scan_top(const int* __restrict__ bsum, int Bs,
                                                   int* __restrict__ boff) {
    __shared__ int sc[1024];
    int t = threadIdx.x;
    int v = (t < Bs) ? bsum[t] : 0;
    sc[t] = v;
    __syncthreads();
    for (int off = 1; off < 1024; off <<= 1) {
        int a = 0;
        if (t >= off) a = sc[t - off];
        __syncthreads();
        sc[t] += a;
        __syncthreads();
    }
    boff[t] = sc[t] - v;  // exclusive
}
__global__ __launch_bounds__(1024) void k_scan_add(int* __restrict__ dstoff,
                                                   const int* __restrict__ boff, int N) {
    int i = blockIdx.x * 1024 + threadIdx.x;
    if (i < N) dstoff[i + 1] += boff[blockIdx.x];
    if (i == 0) dstoff[0] = 0;
}

// ---------------- counting sort by key (block-aggregated) + dst slot assignment ------------
__global__ __launch_bounds__(256) void k_scatter(const int* __restrict__ trip, int E,
                                                 int chunkNodes, int NK,
                                                 const int* __restrict__ dstoff,
                                                 int* __restrict__ cursor_key,
                                                 int* __restrict__ cursor_dst,
                                                 int* __restrict__ srcs,
                                                 int* __restrict__ slotOfPos) {
    __shared__ int cnt[MAXK];
    __shared__ int sbase[MAXK];
    int t = threadIdx.x;
    for (int k = t; k < NK; k += 256) cnt[k] = 0;
    __syncthreads();
    int base = blockIdx.x * 4096;
    int rk[16], ky[16];
#pragma unroll
    for (int i = 0; i < 16; ++i) {
        int e = base + i * 256 + t;
        rk[i] = 0; ky[i] = 0;
        if (e < E) {
            int rel = trip[3 * e + 1], dst = trip[3 * e + 2];
            int key = (dst / chunkNodes) * NREL + rel;
            ky[i] = key;
            rk[i] = atomicAdd(&cnt[key], 1);
        }
    }
    __syncthreads();
    for (int k = t; k < NK; k += 256) {
        int v = cnt[k];
        if (v) sbase[k] = atomicAdd(&cursor_key[k], v);
    }
    __syncthreads();
#pragma unroll
    for (int i = 0; i < 16; ++i) {
        int e = base + i * 256 + t;
        if (e < E) {
            int src = trip[3 * e], dst = trip[3 * e + 2];
            int pos = sbase[ky[i]] + rk[i];
            srcs[pos] = src;
            slotOfPos[pos] = dstoff[dst] + atomicAdd(&cursor_dst[dst], 1);
        }
    }
}

// ---------------- helper: gather one x row -> swizzled bf16 LDS tile ----------------
__device__ __forceinline__ void load_row_bf16(char* As, const float* xrow, int row, int part) {
    const float4* xr = (const float4*)xrow;
#pragma unroll
    for (int jj = 0; jj < 4; ++jj) {
        float4 v0 = xr[part * 8 + 2 * jj];
        float4 v1 = xr[part * 8 + 2 * jj + 1];
        bf16x8 p;
        p[0] = (short)f2bf(v0.x); p[1] = (short)f2bf(v0.y);
        p[2] = (short)f2bf(v0.z); p[3] = (short)f2bf(v0.w);
        p[4] = (short)f2bf(v1.x); p[5] = (short)f2bf(v1.y);
        p[6] = (short)f2bf(v1.z); p[7] = (short)f2bf(v1.w);
        *(bf16x8*)(As + row * 256 + ((((part << 2) + jj) ^ (row & 7)) << 4)) = p;
    }
}
__device__ __forceinline__ void zero_row_bf16(char* As, int row, int part) {
    bf16x8 z = {0, 0, 0, 0, 0, 0, 0, 0};
#pragma unroll
    for (int jj = 0; jj < 4; ++jj)
        *(bf16x8*)(As + row * 256 + ((((part << 2) + jj) ^ (row & 7)) << 4)) = z;
}

// ---------------- phase A: per (chunk, rel, 64-edge tile) MFMA, scatter msg rows -----------
__global__ __launch_bounds__(256) void k_msgs_mm(const float* __restrict__ x,
                                                 const int* __restrict__ srcs,
                                                 const int* __restrict__ slotOfPos,
                                                 const unsigned short* __restrict__ Wbt,
                                                 const int* __restrict__ keyoff,
                                                 const int* __restrict__ tileoff,
                                                 const int* __restrict__ dstoff,
                                                 unsigned short* __restrict__ msgs,
                                                 int c, int chunkNodes, int N) {
    __shared__ bf16x8 AsV[64 * 16];
    __shared__ int sslot[64];
    char* As = (char*)AsV;

    int kbase = c * NREL;
    int bg = tileoff[kbase] + blockIdx.x;
    if (bg >= tileoff[kbase + NREL]) return;
    int lo = kbase, hi = kbase + NREL;
    while (hi - lo > 1) { int mid = (lo + hi) >> 1; if (tileoff[mid] <= bg) lo = mid; else hi = mid; }
    int key = lo, rr = key - kbase;
    int pos0 = keyoff[key] + (bg - tileoff[key]) * 64;
    int count = min(64, keyoff[key + 1] - pos0);
    int loN = min(c * chunkNodes, N);
    int slotBase = dstoff[loN];

    int t = threadIdx.x;
    int row = t >> 2, part = t & 3;
    if (t < 64) sslot[t] = (t < count) ? (slotOfPos[pos0 + t] - slotBase) : 0;
    if (row < count)
        load_row_bf16(As, x + (size_t)srcs[pos0 + row] * NCH, row, part);
    else
        zero_row_bf16(As, row, part);
    __syncthreads();

    int w = t >> 6, lane = t & 63, lr = lane & 15, lg = lane >> 4;
    f32x4 zero = {0.f, 0.f, 0.f, 0.f};
    f32x4 acc[8];
#pragma unroll
    for (int n = 0; n < 8; ++n) acc[n] = zero;
    const char* wb = (const char*)(Wbt + (size_t)rr * NCH * NCH);
    int arow = w * 16 + lr;
#pragma unroll
    for (int kk = 0; kk < 4; ++kk) {
        bf16x8 a = *(const bf16x8*)(As + arow * 256 + ((((kk << 2) + lg) ^ (arow & 7)) << 4));
#pragma unroll
        for (int n = 0; n < 8; ++n) {
            bf16x8 b = *(const bf16x8*)(wb + (((n * 16 + lr) * NCH + kk * 32 + lg * 8) << 1));
            acc[n] = __builtin_amdgcn_mfma_f32_16x16x32_bf16(a, b, acc[n], 0, 0, 0);
        }
    }
#pragma unroll
    for (int n = 0; n < 8; ++n) {
        int col = n * 16 + lr;
#pragma unroll
        for (int j = 0; j < 4; ++j) {
            int rowL = w * 16 + lg * 4 + j;
            if (rowL < count)
                msgs[(size_t)sslot[rowL] * NCH + col] = f2bf(acc[n][j]);
        }
    }
}

// ---------------- phase B: streaming segment-sum per dst ----------------
__global__ __launch_bounds__(256) void k_agg(const unsigned short* __restrict__ msgs,
                                             const int* __restrict__ dstoff,
                                             float* __restrict__ out, int lo, int hi) {
    int t = threadIdx.x, w = t >> 6, lane = t & 63;
    int n = lo + blockIdx.x * 4 + w;
    if (n >= hi) return;
    int base = dstoff[lo];
    int s0 = dstoff[n] - base, s1 = dstoff[n + 1] - base;
    float a0 = 0.f, a1 = 0.f;
    const unsigned* m32 = (const unsigned*)msgs;
    for (int s = s0; s < s1; ++s) {
        unsigned u = m32[(size_t)s * 64 + lane];
        a0 += __uint_as_float(u << 16);
        a1 += __uint_as_float(u & 0xffff0000u);
    }
    float inv = (s1 > s0) ? 1.0f / (float)(s1 - s0) : 0.f;
    float2 o;
    o.x = a0 * inv; o.y = a1 * inv;
    *(float2*)(out + (size_t)n * NCH + lane * 2) = o;
}

// ---------------- out += x @ root_w + root_b (MFMA) ----------------
__global__ __launch_bounds__(256) void k_rootmm(const float* __restrict__ x,
                                                const unsigned short* __restrict__ rwbt,
                                                const float* __restrict__ rb,
                                                float* __restrict__ out, int N) {
    __shared__ bf16x8 AsV[64 * 16];
    char* As = (char*)AsV;
    int n0 = blockIdx.x * 64;
    int t = threadIdx.x, row = t >> 2, part = t & 3;
    if (n0 + row < N)
        load_row_bf16(As, x + (size_t)(n0 + row) * NCH, row, part);
    else
        zero_row_bf16(As, row, part);
    __syncthreads();

    int w = t >> 6, lane = t & 63, lr = lane & 15, lg = lane >> 4;
    f32x4 zero = {0.f, 0.f, 0.f, 0.f};
    f32x4 acc[8];
#pragma unroll
    for (int n = 0; n < 8; ++n) acc[n] = zero;
    const char* wb = (const char*)rwbt;
    int arow = w * 16 + lr;
#pragma unroll
    for (int kk = 0; kk < 4; ++kk) {
        bf16x8 a = *(const bf16x8*)(As + arow * 256 + ((((kk << 2) + lg) ^ (arow & 7)) << 4));
#pragma unroll
        for (int n = 0; n < 8; ++n) {
            bf16x8 b = *(const bf16x8*)(wb + (((n * 16 + lr) * NCH + kk * 32 + lg * 8) << 1));
            acc[n] = __builtin_amdgcn_mfma_f32_16x16x32_bf16(a, b, acc[n], 0, 0, 0);
        }
    }
#pragma unroll
    for (int n = 0; n < 8; ++n) {
        int col = n * 16 + lr;
        float bias = rb[col];
#pragma unroll
        for (int j = 0; j < 4; ++j) {
            int node = n0 + w * 16 + lg * 4 + j;
            if (node < N)
                out[(size_t)node * NCH + col] += acc[n][j] + bias;
        }
    }
}

static inline int imin(int a, int b) { return a < b ? a : b; }

extern "C" void kernel_launch(void* const* d_in, const int* in_sizes, int n_in,
                              void* d_out, int out_size, void* d_ws, size_t ws_size,
                              hipStream_t stream) {
    const float* x = (const float*)d_in[0];
    const int* trip = (const int*)d_in[1];
    const float* basis = (const float*)d_in[3];
    const float* att = (const float*)d_in[4];
    const float* rw = (const float*)d_in[5];
    const float* rb = (const float*)d_in[6];
    float* out = (float*)d_out;

    int N = in_sizes[0] / NCH;
    int E = in_sizes[1] / 3;

    char* ws = (char*)d_ws;
    size_t off = 0;
    auto alloc = [&](size_t b) { size_t o = off; off = (off + b + 255) & ~(size_t)255; return o; };
    size_t oWbt   = alloc((size_t)NREL * NCH * NCH * 2);  // 2 MB
    size_t oRwbt  = alloc((size_t)NCH * NCH * 2);
    size_t oDeg   = alloc((size_t)N * 4);                 // ---- memset zone start
    size_t oCurD  = alloc((size_t)N * 4);
    size_t oHist  = alloc((MAXK + 1) * 4);
    size_t oKeyoff = alloc((MAXK + 1) * 4);               // ---- memset zone end (= oKeyoff)
    size_t oTileoff = alloc((MAXK + 1) * 4);
    size_t oCurK  = alloc((MAXK + 1) * 4);
    size_t oBsum  = alloc(1024 * 4);
    size_t oBoff  = alloc(1024 * 4);
    size_t oDstoff = alloc(((size_t)N + 1) * 4);
    size_t oSrcs  = alloc((size_t)E * 4);
    size_t oSlotOf = alloc((size_t)E * 4);
    size_t oMsgs  = off;

    // pick smallest chunking C such that msgs buffer fits ws
    int C = MAXC;
    size_t cap = (size_t)E / MAXC + (size_t)E / (8 * MAXC) + 2048;
    const int opts[5] = {1, 2, 4, 8, 16};
    for (int i = 0; i < 5; ++i) {
        size_t ce = (opts[i] == 1) ? (size_t)E
                                   : ((size_t)E / opts[i] + (size_t)E / (8 * opts[i]) + 2048);
        if (oMsgs + ce * NCH * 2 <= ws_size) { C = opts[i]; cap = ce; break; }
    }
    int chunkNodes = (N + C - 1) / C;
    int NK = NREL * C;
    int blocksE = (E + 4095) / 4096;
    int Bs = (N + 1023) / 1024;

    int* deg = (int*)(ws + oDeg);
    int* hist = (int*)(ws + oHist);
    int* keyoff = (int*)(ws + oKeyoff);
    int* tileoff = (int*)(ws + oTileoff);
    int* curK = (int*)(ws + oCurK);
    int* curD = (int*)(ws + oCurD);
    int* bsum = (int*)(ws + oBsum);
    int* boff = (int*)(ws + oBoff);
    int* dstoff = (int*)(ws + oDstoff);
    int* srcs = (int*)(ws + oSrcs);
    int* slotOf = (int*)(ws + oSlotOf);
    unsigned short* Wbt = (unsigned short*)(ws + oWbt);
    unsigned short* rwbt = (unsigned short*)(ws + oRwbt);
    unsigned short* msgs = (unsigned short*)(ws + oMsgs);

    hipMemsetAsync(ws + oDeg, 0, oKeyoff - oDeg, stream);  // deg, cursor_dst, hist

    k_buildW<<<NREL + 1, 256, 0, stream>>>(basis, att, rw, Wbt, rwbt);
    k_count<<<blocksE, 256, 0, stream>>>(trip, E, chunkNodes, NK, deg, hist);
    k_scan_keys<<<1, 1024, 0, stream>>>(hist, NK, keyoff, tileoff, curK);
    k_scan_blk<<<Bs, 1024, 0, stream>>>(deg, N, dstoff, bsum);
    k_scan_top<<<1, 1024, 0, stream>>>(bsum, Bs, boff);
    k_scan_add<<<Bs, 1024, 0, stream>>>(dstoff, boff, N);
    k_scatter<<<blocksE, 256, 0, stream>>>(trip, E, chunkNodes, NK, dstoff, curK, curD, srcs, slotOf);

    int TB = (int)(cap / 64) + NREL + 1;
    for (int c = 0; c < C; ++c) {
        k_msgs_mm<<<TB, 256, 0, stream>>>(x, srcs, slotOf, Wbt, keyoff, tileoff, dstoff,
                                          msgs, c, chunkNodes, N);
        int lo = imin(c * chunkNodes, N);
        int hi = imin(lo + chunkNodes, N);
        if (hi > lo)
            k_agg<<<(hi - lo + 3) / 4, 256, 0, stream>>>(msgs, dstoff, out, lo, hi);
    }
    k_rootmm<<<(N + 63) / 64, 256, 0, stream>>>(x, rwbt, rb, out, N);
}

// Round 3
// 574.848 us; speedup vs baseline: 13.5781x; 1.5874x over previous
//
#include <hip/hip_runtime.h>

#define NCH 128
#define NREL 64
#define MAXC 16
#define MAXK (NREL * MAXC)  // 1024
#define TSTRIP 8            // 64-edge tiles per block strip

typedef __attribute__((ext_vector_type(8))) short bf16x8;
typedef __attribute__((ext_vector_type(4))) float f32x4;

__device__ __forceinline__ unsigned short f2bf(float f) {
    unsigned u = __float_as_uint(f);
    return (unsigned short)((u + 0x7fffu + ((u >> 16) & 1u)) >> 16);  // RNE
}
__device__ __forceinline__ unsigned pack2bf(float a, float b) {
    return (unsigned)f2bf(a) | ((unsigned)f2bf(b) << 16);
}

// ---------------- x (fp32) -> x_bf (bf16) ----------------
__global__ __launch_bounds__(256) void k_prep(const float* __restrict__ x,
                                              unsigned short* __restrict__ x_bf,
                                              long total8) {
    long i = (long)blockIdx.x * 256 + threadIdx.x;
    if (i >= total8) return;
    const float4* xp = (const float4*)x;
    float4 v0 = xp[i * 2], v1 = xp[i * 2 + 1];
    bf16x8 p;
    p[0] = (short)f2bf(v0.x); p[1] = (short)f2bf(v0.y);
    p[2] = (short)f2bf(v0.z); p[3] = (short)f2bf(v0.w);
    p[4] = (short)f2bf(v1.x); p[5] = (short)f2bf(v1.y);
    p[6] = (short)f2bf(v1.z); p[7] = (short)f2bf(v1.w);
    ((bf16x8*)x_bf)[i] = p;
}

// ---------------- Wbt[r][oc][ic] bf16 ; rwbt[oc][ic] bf16 ----------------
__global__ __launch_bounds__(256) void k_buildW(const float* __restrict__ basis,
                                                const float* __restrict__ att,
                                                const float* __restrict__ rw,
                                                unsigned short* __restrict__ Wbt,
                                                unsigned short* __restrict__ rwbt) {
    int r = blockIdx.x, t = threadIdx.x;
    if (r < NREL) {
        float a[8];
#pragma unroll
        for (int b = 0; b < 8; ++b) a[b] = att[r * 8 + b];
        for (int idx = t; idx < NCH * NCH; idx += 256) {
            int ic = idx >> 7, oc = idx & 127;
            float s = 0.f;
#pragma unroll
            for (int b = 0; b < 8; ++b) s += a[b] * basis[b * NCH * NCH + ic * NCH + oc];
            Wbt[(size_t)r * NCH * NCH + oc * NCH + ic] = f2bf(s);
        }
    } else {
        for (int idx = t; idx < NCH * NCH; idx += 256) {
            int ic = idx >> 7, oc = idx & 127;
            rwbt[oc * NCH + ic] = f2bf(rw[ic * NCH + oc]);
        }
    }
}

// ---------------- deg[dst]++, hist[key]++ (LDS-aggregated) ----------------
__global__ __launch_bounds__(256) void k_count(const int* __restrict__ trip, int E,
                                               int chunkNodes, int NK,
                                               int* __restrict__ deg, int* __restrict__ hist) {
    __shared__ int h[MAXK];
    int t = threadIdx.x;
    for (int k = t; k < NK; k += 256) h[k] = 0;
    __syncthreads();
    int base = blockIdx.x * 4096;
#pragma unroll 4
    for (int i = 0; i < 16; ++i) {
        int e = base + i * 256 + t;
        if (e < E) {
            int rel = trip[3 * e + 1], dst = trip[3 * e + 2];
            atomicAdd(&h[(dst / chunkNodes) * NREL + rel], 1);
            atomicAdd(&deg[dst], 1);
        }
    }
    __syncthreads();
    for (int k = t; k < NK; k += 256) {
        int v = h[k];
        if (v) atomicAdd(&hist[k], v);
    }
}

// ---------------- scan over keys: keyoff / blkoff(strips) / cursor ----------------
__global__ __launch_bounds__(1024) void k_scan_keys(const int* __restrict__ hist, int NK,
                                                    int* __restrict__ keyoff,
                                                    int* __restrict__ blkoff,
                                                    int* __restrict__ cursor_key) {
    __shared__ int sc[1024], sb[1024];
    int t = threadIdx.x;
    int c = (t < NK) ? hist[t] : 0;
    int strips = (c + 64 * TSTRIP - 1) / (64 * TSTRIP);
    sc[t] = c; sb[t] = strips;
    __syncthreads();
    for (int off = 1; off < 1024; off <<= 1) {
        int a = 0, b = 0;
        if (t >= off) { a = sc[t - off]; b = sb[t - off]; }
        __syncthreads();
        sc[t] += a; sb[t] += b;
        __syncthreads();
    }
    if (t < NK) { keyoff[t] = sc[t] - c; blkoff[t] = sb[t] - strips; cursor_key[t] = sc[t] - c; }
    if (t == NK - 1) { keyoff[NK] = sc[t]; blkoff[NK] = sb[t]; }
}

// ---------------- 3-kernel scan over N (dstoff) ----------------
__global__ __launch_bounds__(1024) void k_scan_blk(const int* __restrict__ deg, int N,
                                                   int* __restrict__ dstoff, int* __restrict__ bsum) {
    __shared__ int sc[1024];
    int t = threadIdx.x, i = blockIdx.x * 1024 + t;
    int v = (i < N) ? deg[i] : 0;
    sc[t] = v;
    __syncthreads();
    for (int off = 1; off < 1024; off <<= 1) {
        int a = 0;
        if (t >= off) a = sc[t - off];
        __syncthreads();
        sc[t] += a;
        __syncthreads();
    }
    if (i < N) dstoff[i + 1] = sc[t];
    if (t == 1023) bsum[blockIdx.x] = sc[1023];
}
__global__ __launch_bounds__(1024) void k_scan_top(const int* __restrict__ bsum, int Bs,
                                                   int* __restrict__ boff) {
    __shared__ int sc[1024];
    int t = threadIdx.x;
    int v = (t < Bs) ? bsum[t] : 0;
    sc[t] = v;
    __syncthreads();
    for (int off = 1; off < 1024; off <<= 1) {
        int a = 0;
        if (t >= off) a = sc[t - off];
        __syncthreads();
        sc[t] += a;
        __syncthreads();
    }
    boff[t] = sc[t] - v;
}
__global__ __launch_bounds__(1024) void k_scan_add(int* __restrict__ dstoff,
                                                   const int* __restrict__ boff, int N) {
    int i = blockIdx.x * 1024 + threadIdx.x;
    if (i < N) dstoff[i + 1] += boff[blockIdx.x];
    if (i == 0) dstoff[0] = 0;
}

// ---------------- counting sort by key + dst slot assignment ----------------
__global__ __launch_bounds__(256) void k_scatter(const int* __restrict__ trip, int E,
                                                 int chunkNodes, int NK,
                                                 const int* __restrict__ dstoff,
                                                 int* __restrict__ cursor_key,
                                                 int* __restrict__ cursor_dst,
                                                 int* __restrict__ srcs,
                                                 int* __restrict__ slotOfPos) {
    __shared__ int cnt[MAXK];
    __shared__ int sbase[MAXK];
    int t = threadIdx.x;
    for (int k = t; k < NK; k += 256) cnt[k] = 0;
    __syncthreads();
    int base = blockIdx.x * 4096;
    int rk[16], ky[16];
#pragma unroll
    for (int i = 0; i < 16; ++i) {
        int e = base + i * 256 + t;
        rk[i] = 0; ky[i] = 0;
        if (e < E) {
            int rel = trip[3 * e + 1], dst = trip[3 * e + 2];
            int key = (dst / chunkNodes) * NREL + rel;
            ky[i] = key;
            rk[i] = atomicAdd(&cnt[key], 1);
        }
    }
    __syncthreads();
    for (int k = t; k < NK; k += 256) {
        int v = cnt[k];
        if (v) sbase[k] = atomicAdd(&cursor_key[k], v);
    }
    __syncthreads();
#pragma unroll
    for (int i = 0; i < 16; ++i) {
        int e = base + i * 256 + t;
        if (e < E) {
            int src = trip[3 * e], dst = trip[3 * e + 2];
            int pos = sbase[ky[i]] + rk[i];
            srcs[pos] = src;
            slotOfPos[pos] = dstoff[dst] + atomicAdd(&cursor_dst[dst], 1);
        }
    }
}

// ---------------- phase A: strip-mined per-rel MFMA; W in regs; dbuf LDS ----------------
__global__ __launch_bounds__(256, 4) void k_msgs_mm(const unsigned short* __restrict__ x_bf,
                                                    const int* __restrict__ srcs,
                                                    const int* __restrict__ slotOf,
                                                    const unsigned short* __restrict__ Wbt,
                                                    const int* __restrict__ keyoff,
                                                    const int* __restrict__ blkoff,
                                                    const int* __restrict__ dstoff,
                                                    unsigned short* __restrict__ msgs,
                                                    int c, int chunkNodes, int N) {
    __shared__ bf16x8 AsV[2 * 1024];  // 2 x 16KB
    __shared__ int sslot[2][64];
    char* AsBase = (char*)AsV;

    int kbase = c * NREL;
    int bg = blkoff[kbase] + blockIdx.x;
    if (bg >= blkoff[kbase + NREL]) return;
    int lo = kbase, hi = kbase + NREL;
    while (hi - lo > 1) { int mid = (lo + hi) >> 1; if (blkoff[mid] <= bg) lo = mid; else hi = mid; }
    int key = lo, rr = key - kbase;
    int pbase = keyoff[key];
    int cnt_key = keyoff[key + 1] - pbase;
    int tile0 = (bg - blkoff[key]) * TSTRIP;
    int ntile = min(TSTRIP, ((cnt_key + 63) >> 6) - tile0);
    int slotBase = dstoff[min(c * chunkNodes, N)];

    int t = threadIdx.x;
    int w = t >> 6, lane = t & 63, lr = lane & 15, lg = lane >> 4;
    int row = t >> 2, part = t & 3;

    // W fragments: loaded once, held in registers for the whole strip
    bf16x8 a8[8];
    const unsigned short* wr = Wbt + (size_t)rr * NCH * NCH;
#pragma unroll
    for (int ni = 0; ni < 2; ++ni)
#pragma unroll
        for (int kk = 0; kk < 4; ++kk)
            a8[ni * 4 + kk] = *(const bf16x8*)(wr + ((w * 2 + ni) * 16 + lr) * NCH + kk * 32 + lg * 8);

    const bf16x8 bz = {0, 0, 0, 0, 0, 0, 0, 0};
    bf16x8 p0 = bz, p1 = bz, p2 = bz, p3 = bz;
    int sreg = 0;

    {   // load tile0 into regs
        int pos0 = pbase + tile0 * 64;
        int cntt = min(64, cnt_key - tile0 * 64);
        if (row < cntt) {
            const bf16x8* xr = (const bf16x8*)(x_bf + (size_t)srcs[pos0 + row] * NCH);
            p0 = xr[part * 4 + 0]; p1 = xr[part * 4 + 1];
            p2 = xr[part * 4 + 2]; p3 = xr[part * 4 + 3];
        }
        if (t < 64) sreg = (t < cntt) ? (slotOf[pos0 + t] - slotBase) : 0;
    }

    int cur = 0;
    for (int ti = 0; ti < ntile; ++ti) {
        char* A = AsBase + cur * 16384;
        *(bf16x8*)(A + row * 256 + (((part * 4 + 0) ^ (row & 7)) << 4)) = p0;
        *(bf16x8*)(A + row * 256 + (((part * 4 + 1) ^ (row & 7)) << 4)) = p1;
        *(bf16x8*)(A + row * 256 + (((part * 4 + 2) ^ (row & 7)) << 4)) = p2;
        *(bf16x8*)(A + row * 256 + (((part * 4 + 3) ^ (row & 7)) << 4)) = p3;
        if (t < 64) sslot[cur][t] = sreg;
        int cntc = min(64, cnt_key - (tile0 + ti) * 64);

        if (ti + 1 < ntile) {  // prefetch next tile (latency hides under MFMA)
            int tn = tile0 + ti + 1;
            int pos0 = pbase + tn * 64;
            int cntt = min(64, cnt_key - tn * 64);
            if (row < cntt) {
                const bf16x8* xr = (const bf16x8*)(x_bf + (size_t)srcs[pos0 + row] * NCH);
                p0 = xr[part * 4 + 0]; p1 = xr[part * 4 + 1];
                p2 = xr[part * 4 + 2]; p3 = xr[part * 4 + 3];
            } else { p0 = bz; p1 = bz; p2 = bz; p3 = bz; }
            if (t < 64) sreg = (t < cntt) ? (slotOf[pos0 + t] - slotBase) : 0;
        }
        __syncthreads();

        f32x4 acc[2][4];
#pragma unroll
        for (int ni = 0; ni < 2; ++ni)
#pragma unroll
            for (int et = 0; et < 4; ++et) acc[ni][et] = (f32x4){0.f, 0.f, 0.f, 0.f};

#pragma unroll
        for (int kk = 0; kk < 4; ++kk)
#pragma unroll
            for (int et = 0; et < 4; ++et) {
                int erow = et * 16 + lr;
                bf16x8 b = *(const bf16x8*)(A + erow * 256 + ((((kk << 2) + lg) ^ (erow & 7)) << 4));
                acc[0][et] = __builtin_amdgcn_mfma_f32_16x16x32_bf16(a8[0 + kk], b, acc[0][et], 0, 0, 0);
                acc[1][et] = __builtin_amdgcn_mfma_f32_16x16x32_bf16(a8[4 + kk], b, acc[1][et], 0, 0, 0);
            }

        int slt[4];
#pragma unroll
        for (int et = 0; et < 4; ++et) slt[et] = sslot[cur][et * 16 + lr];
#pragma unroll
        for (int ni = 0; ni < 2; ++ni) {
            int oc0 = (w * 2 + ni) * 16 + lg * 4;
#pragma unroll
            for (int et = 0; et < 4; ++et) {
                int edge = et * 16 + lr;
                if (edge < cntc) {
                    f32x4 v = acc[ni][et];
                    uint2 u;
                    u.x = pack2bf(v[0], v[1]);
                    u.y = pack2bf(v[2], v[3]);
                    *(uint2*)(msgs + (size_t)slt[et] * NCH + oc0) = u;
                }
            }
        }
        cur ^= 1;
    }
}

// ---------------- phase B: streaming segment-sum per dst (out +=) ----------------
__global__ __launch_bounds__(256) void k_agg(const unsigned short* __restrict__ msgs,
                                             const int* __restrict__ dstoff,
                                             float* __restrict__ out, int lo, int hi) {
    int t = threadIdx.x, w = t >> 6, lane = t & 63;
    int n = lo + blockIdx.x * 4 + w;
    if (n >= hi) return;
    int base = dstoff[lo];
    int s0 = dstoff[n] - base, s1 = dstoff[n + 1] - base;
    float a0 = 0.f, a1 = 0.f;
    const unsigned* m32 = (const unsigned*)msgs;
    for (int s = s0; s < s1; ++s) {
        unsigned u = m32[(size_t)s * 64 + lane];
        a0 += __uint_as_float(u << 16);
        a1 += __uint_as_float(u & 0xffff0000u);
    }
    float inv = (s1 > s0) ? 1.0f / (float)(s1 - s0) : 0.f;
    float2* op = (float2*)(out + (size_t)n * NCH + lane * 2);
    float2 o = *op;
    o.x += a0 * inv; o.y += a1 * inv;
    *op = o;
}

// ---------------- out = x @ root_w + root_b (writes, runs before k_agg) ----------------
__global__ __launch_bounds__(256) void k_rootmm(const unsigned short* __restrict__ x_bf,
                                                const unsigned short* __restrict__ rwbt,
                                                const float* __restrict__ rb,
                                                float* __restrict__ out, int N) {
    __shared__ bf16x8 AsV[1024];
    char* A = (char*)AsV;
    int n0 = blockIdx.x * 64;
    int t = threadIdx.x, w = t >> 6, lane = t & 63, lr = lane & 15, lg = lane >> 4;
    int row = t >> 2, part = t & 3;
    int cnt = min(64, N - n0);

    bf16x8 a8[8];
#pragma unroll
    for (int ni = 0; ni < 2; ++ni)
#pragma unroll
        for (int kk = 0; kk < 4; ++kk)
            a8[ni * 4 + kk] = *(const bf16x8*)(rwbt + ((w * 2 + ni) * 16 + lr) * NCH + kk * 32 + lg * 8);
    f32x4 bias[2];
#pragma unroll
    for (int ni = 0; ni < 2; ++ni) bias[ni] = *(const f32x4*)(rb + (w * 2 + ni) * 16 + lg * 4);

    const bf16x8 bz = {0, 0, 0, 0, 0, 0, 0, 0};
    if (row < cnt) {
        const bf16x8* xr = (const bf16x8*)(x_bf + (size_t)(n0 + row) * NCH);
#pragma unroll
        for (int jj = 0; jj < 4; ++jj)
            *(bf16x8*)(A + row * 256 + (((part * 4 + jj) ^ (row & 7)) << 4)) = xr[part * 4 + jj];
    } else {
#pragma unroll
        for (int jj = 0; jj < 4; ++jj)
            *(bf16x8*)(A + row * 256 + (((part * 4 + jj) ^ (row & 7)) << 4)) = bz;
    }
    __syncthreads();

    f32x4 acc[2][4];
#pragma unroll
    for (int ni = 0; ni < 2; ++ni)
#pragma unroll
        for (int et = 0; et < 4; ++et) acc[ni][et] = (f32x4){0.f, 0.f, 0.f, 0.f};
#pragma unroll
    for (int kk = 0; kk < 4; ++kk)
#pragma unroll
        for (int et = 0; et < 4; ++et) {
            int erow = et * 16 + lr;
            bf16x8 b = *(const bf16x8*)(A + erow * 256 + ((((kk << 2) + lg) ^ (erow & 7)) << 4));
            acc[0][et] = __builtin_amdgcn_mfma_f32_16x16x32_bf16(a8[0 + kk], b, acc[0][et], 0, 0, 0);
            acc[1][et] = __builtin_amdgcn_mfma_f32_16x16x32_bf16(a8[4 + kk], b, acc[1][et], 0, 0, 0);
        }

#pragma unroll
    for (int ni = 0; ni < 2; ++ni) {
        int oc0 = (w * 2 + ni) * 16 + lg * 4;
#pragma unroll
        for (int et = 0; et < 4; ++et) {
            int node = n0 + et * 16 + lr;
            if (node < N) {
                f32x4 v = acc[ni][et] + bias[ni];
                *(f32x4*)(out + (size_t)node * NCH + oc0) = v;
            }
        }
    }
}

static inline int imin(int a, int b) { return a < b ? a : b; }

extern "C" void kernel_launch(void* const* d_in, const int* in_sizes, int n_in,
                              void* d_out, int out_size, void* d_ws, size_t ws_size,
                              hipStream_t stream) {
    const float* x = (const float*)d_in[0];
    const int* trip = (const int*)d_in[1];
    const float* basis = (const float*)d_in[3];
    const float* att = (const float*)d_in[4];
    const float* rw = (const float*)d_in[5];
    const float* rb = (const float*)d_in[6];
    float* out = (float*)d_out;

    int N = in_sizes[0] / NCH;
    int E = in_sizes[1] / 3;

    char* ws = (char*)d_ws;
    size_t off = 0;
    auto alloc = [&](size_t b) { size_t o = off; off = (off + b + 255) & ~(size_t)255; return o; };
    size_t oWbt  = alloc((size_t)NREL * NCH * NCH * 2);  // 2 MB
    size_t oRwbt = alloc((size_t)NCH * NCH * 2);
    size_t oXbf  = alloc((size_t)N * NCH * 2);           // 25.6 MB
    size_t oDeg  = alloc((size_t)N * 4);                 // ---- memset zone start
    size_t oCurD = alloc((size_t)N * 4);
    size_t oHist = alloc((MAXK + 1) * 4);
    size_t oKeyoff = alloc((MAXK + 1) * 4);              // ---- memset zone end
    size_t oBlkoff = alloc((MAXK + 1) * 4);
    size_t oCurK = alloc((MAXK + 1) * 4);
    size_t oBsum = alloc(1024 * 4);
    size_t oBoff = alloc(1024 * 4);
    size_t oDstoff = alloc(((size_t)N + 1) * 4);
    size_t oSrcs = alloc((size_t)E * 4);
    size_t oSlotOf = alloc((size_t)E * 4);
    size_t oMsgs = off;

    int C = MAXC;
    size_t cap = (size_t)E / MAXC + (size_t)E / (8 * MAXC) + 2048;
    const int opts[5] = {1, 2, 4, 8, 16};
    for (int i = 0; i < 5; ++i) {
        size_t ce = (opts[i] == 1) ? (size_t)E
                                   : ((size_t)E / opts[i] + (size_t)E / (8 * opts[i]) + 2048);
        if (oMsgs + ce * NCH * 2 <= ws_size) { C = opts[i]; cap = ce; break; }
    }
    int chunkNodes = (N + C - 1) / C;
    int NK = NREL * C;
    int blocksE = (E + 4095) / 4096;
    int Bs = (N + 1023) / 1024;

    int* deg = (int*)(ws + oDeg);
    int* hist = (int*)(ws + oHist);
    int* keyoff = (int*)(ws + oKeyoff);
    int* blkoff = (int*)(ws + oBlkoff);
    int* curK = (int*)(ws + oCurK);
    int* curD = (int*)(ws + oCurD);
    int* bsum = (int*)(ws + oBsum);
    int* boff = (int*)(ws + oBoff);
    int* dstoff = (int*)(ws + oDstoff);
    int* srcs = (int*)(ws + oSrcs);
    int* slotOf = (int*)(ws + oSlotOf);
    unsigned short* Wbt = (unsigned short*)(ws + oWbt);
    unsigned short* rwbt = (unsigned short*)(ws + oRwbt);
    unsigned short* x_bf = (unsigned short*)(ws + oXbf);
    unsigned short* msgs = (unsigned short*)(ws + oMsgs);

    hipMemsetAsync(ws + oDeg, 0, oKeyoff - oDeg, stream);  // deg, cursor_dst, hist

    long total8 = (long)N * NCH / 8;
    k_prep<<<(int)((total8 + 255) / 256), 256, 0, stream>>>(x, x_bf, total8);
    k_buildW<<<NREL + 1, 256, 0, stream>>>(basis, att, rw, Wbt, rwbt);
    k_count<<<blocksE, 256, 0, stream>>>(trip, E, chunkNodes, NK, deg, hist);
    k_scan_keys<<<1, 1024, 0, stream>>>(hist, NK, keyoff, blkoff, curK);
    k_scan_blk<<<Bs, 1024, 0, stream>>>(deg, N, dstoff, bsum);
    k_scan_top<<<1, 1024, 0, stream>>>(bsum, Bs, boff);
    k_scan_add<<<Bs, 1024, 0, stream>>>(dstoff, boff, N);
    k_scatter<<<blocksE, 256, 0, stream>>>(trip, E, chunkNodes, NK, dstoff, curK, curD, srcs, slotOf);

    k_rootmm<<<(N + 63) / 64, 256, 0, stream>>>(x_bf, rwbt, rb, out, N);

    int TB = (int)(cap / (64 * TSTRIP)) + NREL + 1;
    for (int c = 0; c < C; ++c) {
        k_msgs_mm<<<TB, 256, 0, stream>>>(x_bf, srcs, slotOf, Wbt, keyoff, blkoff, dstoff,
                                          msgs, c, chunkNodes, N);
        int lo = imin(c * chunkNodes, N);
        int hi = imin(lo + chunkNodes, N);
        if (hi > lo)
            k_agg<<<(hi - lo + 3) / 4, 256, 0, stream>>>(msgs, dstoff, out, lo, hi);
    }
}

// Round 4
// 544.672 us; speedup vs baseline: 14.3303x; 1.0554x over previous
//
#include <hip/hip_runtime.h>

#define NCH 128
#define NREL 64
#define MAXC 16
#define MAXK (NREL * MAXC)  // 1024
#define TSTRIP 8            // 64-edge tiles per block strip
#define ESB 1024            // edges per count/scatter block

typedef __attribute__((ext_vector_type(8))) short bf16x8;
typedef __attribute__((ext_vector_type(4))) float f32x4;

__device__ __forceinline__ unsigned short f2bf(float f) {
    unsigned u = __float_as_uint(f);
    return (unsigned short)((u + 0x7fffu + ((u >> 16) & 1u)) >> 16);  // RNE
}
__device__ __forceinline__ unsigned pack2bf(float a, float b) {
    return (unsigned)f2bf(a) | ((unsigned)f2bf(b) << 16);
}

// ---------------- x (fp32) -> x_bf (bf16) ----------------
__global__ __launch_bounds__(256) void k_prep(const float* __restrict__ x,
                                              unsigned short* __restrict__ x_bf,
                                              long total8) {
    long i = (long)blockIdx.x * 256 + threadIdx.x;
    if (i >= total8) return;
    const float4* xp = (const float4*)x;
    float4 v0 = xp[i * 2], v1 = xp[i * 2 + 1];
    bf16x8 p;
    p[0] = (short)f2bf(v0.x); p[1] = (short)f2bf(v0.y);
    p[2] = (short)f2bf(v0.z); p[3] = (short)f2bf(v0.w);
    p[4] = (short)f2bf(v1.x); p[5] = (short)f2bf(v1.y);
    p[6] = (short)f2bf(v1.z); p[7] = (short)f2bf(v1.w);
    ((bf16x8*)x_bf)[i] = p;
}

// ---------------- Wbt[r][oc][ic] bf16 ; rwbt[oc][ic] bf16 ----------------
__global__ __launch_bounds__(256) void k_buildW(const float* __restrict__ basis,
                                                const float* __restrict__ att,
                                                const float* __restrict__ rw,
                                                unsigned short* __restrict__ Wbt,
                                                unsigned short* __restrict__ rwbt) {
    int r = blockIdx.x, t = threadIdx.x;
    if (r < NREL) {
        float a[8];
#pragma unroll
        for (int b = 0; b < 8; ++b) a[b] = att[r * 8 + b];
        for (int idx = t; idx < NCH * NCH; idx += 256) {
            int ic = idx >> 7, oc = idx & 127;
            float s = 0.f;
#pragma unroll
            for (int b = 0; b < 8; ++b) s += a[b] * basis[b * NCH * NCH + ic * NCH + oc];
            Wbt[(size_t)r * NCH * NCH + oc * NCH + ic] = f2bf(s);
        }
    } else {
        for (int idx = t; idx < NCH * NCH; idx += 256) {
            int ic = idx >> 7, oc = idx & 127;
            rwbt[oc * NCH + ic] = f2bf(rw[ic * NCH + oc]);
        }
    }
}

// ---------------- deg[dst]++ (rank saved), hist[key]++ ----------------
__global__ __launch_bounds__(256) void k_count(const int* __restrict__ trip, int E,
                                               int chunkNodes, int NK,
                                               int* __restrict__ deg, int* __restrict__ hist,
                                               int* __restrict__ rankOf) {
    __shared__ int h[MAXK];
    int t = threadIdx.x;
    for (int k = t; k < NK; k += 256) h[k] = 0;
    __syncthreads();
    int base = blockIdx.x * ESB;
#pragma unroll
    for (int i = 0; i < ESB / 256; ++i) {
        int e = base + i * 256 + t;
        if (e < E) {
            int rel = trip[3 * e + 1], dst = trip[3 * e + 2];
            atomicAdd(&h[(dst / chunkNodes) * NREL + rel], 1);
            rankOf[e] = atomicAdd(&deg[dst], 1);
        }
    }
    __syncthreads();
    for (int k = t; k < NK; k += 256) {
        int v = h[k];
        if (v) atomicAdd(&hist[k], v);
    }
}

// ---------------- scan over keys: keyoff / blkoff(strips) / cursor ----------------
__global__ __launch_bounds__(1024) void k_scan_keys(const int* __restrict__ hist, int NK,
                                                    int* __restrict__ keyoff,
                                                    int* __restrict__ blkoff,
                                                    int* __restrict__ cursor_key) {
    __shared__ int sc[1024], sb[1024];
    int t = threadIdx.x;
    int c = (t < NK) ? hist[t] : 0;
    int strips = (c + 64 * TSTRIP - 1) / (64 * TSTRIP);
    sc[t] = c; sb[t] = strips;
    __syncthreads();
    for (int off = 1; off < 1024; off <<= 1) {
        int a = 0, b = 0;
        if (t >= off) { a = sc[t - off]; b = sb[t - off]; }
        __syncthreads();
        sc[t] += a; sb[t] += b;
        __syncthreads();
    }
    if (t < NK) { keyoff[t] = sc[t] - c; blkoff[t] = sb[t] - strips; cursor_key[t] = sc[t] - c; }
    if (t == NK - 1) { keyoff[NK] = sc[t]; blkoff[NK] = sb[t]; }
}

// ---------------- 3-kernel scan over N (dstoff) ----------------
__global__ __launch_bounds__(1024) void k_scan_blk(const int* __restrict__ deg, int N,
                                                   int* __restrict__ dstoff, int* __restrict__ bsum) {
    __shared__ int sc[1024];
    int t = threadIdx.x, i = blockIdx.x * 1024 + t;
    int v = (i < N) ? deg[i] : 0;
    sc[t] = v;
    __syncthreads();
    for (int off = 1; off < 1024; off <<= 1) {
        int a = 0;
        if (t >= off) a = sc[t - off];
        __syncthreads();
        sc[t] += a;
        __syncthreads();
    }
    if (i < N) dstoff[i + 1] = sc[t];
    if (t == 1023) bsum[blockIdx.x] = sc[1023];
}
__global__ __launch_bounds__(1024) void k_scan_top(const int* __restrict__ bsum, int Bs,
                                                   int* __restrict__ boff) {
    __shared__ int sc[1024];
    int t = threadIdx.x;
    int v = (t < Bs) ? bsum[t] : 0;
    sc[t] = v;
    __syncthreads();
    for (int off = 1; off < 1024; off <<= 1) {
        int a = 0;
        if (t >= off) a = sc[t - off];
        __syncthreads();
        sc[t] += a;
        __syncthreads();
    }
    boff[t] = sc[t] - v;
}
__global__ __launch_bounds__(1024) void k_scan_add(int* __restrict__ dstoff,
                                                   const int* __restrict__ boff, int N) {
    int i = blockIdx.x * 1024 + threadIdx.x;
    if (i < N) dstoff[i + 1] += boff[blockIdx.x];
    if (i == 0) dstoff[0] = 0;
}

// ---------------- counting sort by key, LDS-staged coalesced output ----------------
__global__ __launch_bounds__(256) void k_scatter(const int* __restrict__ trip, int E,
                                                 int chunkNodes, int NK,
                                                 const int* __restrict__ dstoff,
                                                 const int* __restrict__ rankOf,
                                                 int* __restrict__ cursor_key,
                                                 int* __restrict__ srcs,
                                                 int* __restrict__ slotOfPos) {
    __shared__ int cnt[MAXK], lbase[MAXK], delta[MAXK];
    __shared__ int ssc[256];
    __shared__ int lsrc[ESB], lslot[ESB];
    __shared__ unsigned short lkey[ESB];
    int t = threadIdx.x;
    for (int k = t; k < NK; k += 256) cnt[k] = 0;
    __syncthreads();
    int base = blockIdx.x * ESB;
    int total = min(ESB, E - base);

    int rk[ESB / 256];
    unsigned short ky[ESB / 256];
#pragma unroll
    for (int i = 0; i < ESB / 256; ++i) {
        int e = base + i * 256 + t;
        rk[i] = 0; ky[i] = 0;
        if (e < E) {
            int rel = trip[3 * e + 1], dst = trip[3 * e + 2];
            int key = (dst / chunkNodes) * NREL + rel;
            ky[i] = (unsigned short)key;
            rk[i] = atomicAdd(&cnt[key], 1);
        }
    }
    __syncthreads();

    // exclusive scan cnt -> lbase (256 threads over NK<=1024)
    int ch = (NK + 255) >> 8;
    int mysum = 0;
#pragma unroll 4
    for (int i = 0; i < ch; ++i) {
        int idx = t * ch + i;
        if (idx < NK) mysum += cnt[idx];
    }
    ssc[t] = mysum;
    __syncthreads();
    for (int off = 1; off < 256; off <<= 1) {
        int a = 0;
        if (t >= off) a = ssc[t - off];
        __syncthreads();
        ssc[t] += a;
        __syncthreads();
    }
    int run = ssc[t] - mysum;
#pragma unroll 4
    for (int i = 0; i < ch; ++i) {
        int idx = t * ch + i;
        if (idx < NK) { lbase[idx] = run; run += cnt[idx]; }
    }
    __syncthreads();
    for (int k = t; k < NK; k += 256) {
        int v = cnt[k];
        if (v) delta[k] = atomicAdd(&cursor_key[k], v) - lbase[k];
    }
    __syncthreads();

#pragma unroll
    for (int i = 0; i < ESB / 256; ++i) {
        int e = base + i * 256 + t;
        if (e < E) {
            int src = trip[3 * e], dst = trip[3 * e + 2];
            int j = lbase[ky[i]] + rk[i];
            lsrc[j] = src;
            lslot[j] = dstoff[dst] + rankOf[e];
            lkey[j] = ky[i];
        }
    }
    __syncthreads();
    for (int j = t; j < total; j += 256) {
        int g = delta[lkey[j]] + j;
        srcs[g] = lsrc[j];
        slotOfPos[g] = lslot[j];
    }
}

// ---------------- phase A: strip-mined per-rel MFMA; full-line gather & store --------------
__global__ __launch_bounds__(256, 4) void k_msgs_mm(const unsigned short* __restrict__ x_bf,
                                                    const int* __restrict__ srcs,
                                                    const int* __restrict__ slotOf,
                                                    const unsigned short* __restrict__ Wbt,
                                                    const int* __restrict__ keyoff,
                                                    const int* __restrict__ blkoff,
                                                    const int* __restrict__ dstoff,
                                                    unsigned short* __restrict__ msgs,
                                                    int c, int chunkNodes, int N) {
    __shared__ bf16x8 AsV[1024];   // 16KB A tile (single buffer; sync-protected)
    __shared__ bf16x8 OsV[1024];   // 16KB output staging
    __shared__ int sslot[2][64];
    char* A = (char*)AsV;
    char* Os = (char*)OsV;

    int kbase = c * NREL;
    int bg = blkoff[kbase] + blockIdx.x;
    if (bg >= blkoff[kbase + NREL]) return;
    int lo = kbase, hi = kbase + NREL;
    while (hi - lo > 1) { int mid = (lo + hi) >> 1; if (blkoff[mid] <= bg) lo = mid; else hi = mid; }
    int key = lo, rr = key - kbase;
    int pbase = keyoff[key];
    int cnt_key = keyoff[key + 1] - pbase;
    int tile0 = (bg - blkoff[key]) * TSTRIP;
    int ntile = min(TSTRIP, ((cnt_key + 63) >> 6) - tile0);
    int slotBase = dstoff[min(c * chunkNodes, N)];

    int t = threadIdx.x;
    int w = t >> 6, lane = t & 63, lr = lane & 15, lg = lane >> 4;
    int row = t >> 2, part = t & 3;

    // W fragments: loaded once, held in registers for the whole strip
    bf16x8 a8[8];
    const unsigned short* wr = Wbt + (size_t)rr * NCH * NCH;
#pragma unroll
    for (int ni = 0; ni < 2; ++ni)
#pragma unroll
        for (int kk = 0; kk < 4; ++kk)
            a8[ni * 4 + kk] = *(const bf16x8*)(wr + ((w * 2 + ni) * 16 + lr) * NCH + kk * 32 + lg * 8);

    const bf16x8 bz = {0, 0, 0, 0, 0, 0, 0, 0};
    bf16x8 p0 = bz, p1 = bz, p2 = bz, p3 = bz;  // p_j = row 16B-unit (j*4 + part)
    int sreg = 0;

    {   // load tile0 into regs: lane-quad reads one contiguous 64B line per instr
        int pos0 = pbase + tile0 * 64;
        int cntt = min(64, cnt_key - tile0 * 64);
        if (row < cntt) {
            const bf16x8* xr = (const bf16x8*)(x_bf + (size_t)srcs[pos0 + row] * NCH);
            p0 = xr[0 * 4 + part]; p1 = xr[1 * 4 + part];
            p2 = xr[2 * 4 + part]; p3 = xr[3 * 4 + part];
        }
        if (t < 64) sreg = (t < cntt) ? (slotOf[pos0 + t] - slotBase) : 0;
    }

    int cur = 0;
    for (int ti = 0; ti < ntile; ++ti) {
        // stage A from regs (unit index = j*4 + part)
        *(bf16x8*)(A + row * 256 + ((((0 << 2) + part) ^ (row & 7)) << 4)) = p0;
        *(bf16x8*)(A + row * 256 + ((((1 << 2) + part) ^ (row & 7)) << 4)) = p1;
        *(bf16x8*)(A + row * 256 + ((((2 << 2) + part) ^ (row & 7)) << 4)) = p2;
        *(bf16x8*)(A + row * 256 + ((((3 << 2) + part) ^ (row & 7)) << 4)) = p3;
        if (t < 64) sslot[cur][t] = sreg;
        int cntc = min(64, cnt_key - (tile0 + ti) * 64);

        if (ti + 1 < ntile) {  // prefetch next tile under this tile's compute
            int tn = tile0 + ti + 1;
            int pos0 = pbase + tn * 64;
            int cntt = min(64, cnt_key - tn * 64);
            if (row < cntt) {
                const bf16x8* xr = (const bf16x8*)(x_bf + (size_t)srcs[pos0 + row] * NCH);
                p0 = xr[0 * 4 + part]; p1 = xr[1 * 4 + part];
                p2 = xr[2 * 4 + part]; p3 = xr[3 * 4 + part];
            } else { p0 = bz; p1 = bz; p2 = bz; p3 = bz; }
            if (t < 64) sreg = (t < cntt) ? (slotOf[pos0 + t] - slotBase) : 0;
        }
        __syncthreads();  // A + sslot[cur] ready

        f32x4 acc[2][4];
#pragma unroll
        for (int ni = 0; ni < 2; ++ni)
#pragma unroll
            for (int et = 0; et < 4; ++et) acc[ni][et] = (f32x4){0.f, 0.f, 0.f, 0.f};

#pragma unroll
        for (int kk = 0; kk < 4; ++kk)
#pragma unroll
            for (int et = 0; et < 4; ++et) {
                int erow = et * 16 + lr;
                bf16x8 b = *(const bf16x8*)(A + erow * 256 + ((((kk << 2) + lg) ^ (erow & 7)) << 4));
                acc[0][et] = __builtin_amdgcn_mfma_f32_16x16x32_bf16(a8[0 + kk], b, acc[0][et], 0, 0, 0);
                acc[1][et] = __builtin_amdgcn_mfma_f32_16x16x32_bf16(a8[4 + kk], b, acc[1][et], 0, 0, 0);
            }

        // acc -> Os (swizzled, bf16): row-major [edge][oc]
#pragma unroll
        for (int ni = 0; ni < 2; ++ni) {
            int unitB = (w * 2 + ni) * 2 + (lg >> 1);
            int sub = (lg & 1) << 3;
#pragma unroll
            for (int et = 0; et < 4; ++et) {
                int erow = et * 16 + lr;
                f32x4 v = acc[ni][et];
                uint2 u;
                u.x = pack2bf(v[0], v[1]);
                u.y = pack2bf(v[2], v[3]);
                *(uint2*)(Os + erow * 256 + ((unitB ^ (erow & 7)) << 4) + sub) = u;
            }
        }
        __syncthreads();  // Os ready; all MFMA reads of A done

        // each thread stores one contiguous 64B chunk of one row (full lines)
        if (row < cntc) {
            int slot = sslot[cur][row];
            unsigned short* dp = msgs + (size_t)slot * NCH + part * 32;
#pragma unroll
            for (int jj = 0; jj < 4; ++jj) {
                bf16x8 v = *(const bf16x8*)(Os + row * 256 + ((((part << 2) + jj) ^ (row & 7)) << 4));
                *(bf16x8*)(dp + jj * 8) = v;
            }
        }
        cur ^= 1;
    }
}

// ---------------- phase B: streaming segment-sum per dst (out +=) ----------------
__global__ __launch_bounds__(256) void k_agg(const unsigned short* __restrict__ msgs,
                                             const int* __restrict__ dstoff,
                                             float* __restrict__ out, int lo, int hi) {
    int t = threadIdx.x, w = t >> 6, lane = t & 63;
    int n = lo + blockIdx.x * 4 + w;
    if (n >= hi) return;
    int base = dstoff[lo];
    int s0 = dstoff[n] - base, s1 = dstoff[n + 1] - base;
    float a0 = 0.f, a1 = 0.f;
    const unsigned* m32 = (const unsigned*)msgs;
    for (int s = s0; s < s1; ++s) {
        unsigned u = m32[(size_t)s * 64 + lane];
        a0 += __uint_as_float(u << 16);
        a1 += __uint_as_float(u & 0xffff0000u);
    }
    float inv = (s1 > s0) ? 1.0f / (float)(s1 - s0) : 0.f;
    float2* op = (float2*)(out + (size_t)n * NCH + lane * 2);
    float2 o = *op;
    o.x += a0 * inv; o.y += a1 * inv;
    *op = o;
}

// ---------------- out = x @ root_w + root_b ----------------
__global__ __launch_bounds__(256) void k_rootmm(const unsigned short* __restrict__ x_bf,
                                                const unsigned short* __restrict__ rwbt,
                                                const float* __restrict__ rb,
                                                float* __restrict__ out, int N) {
    __shared__ bf16x8 AsV[1024];
    char* A = (char*)AsV;
    int n0 = blockIdx.x * 64;
    int t = threadIdx.x, w = t >> 6, lane = t & 63, lr = lane & 15, lg = lane >> 4;
    int row = t >> 2, part = t & 3;
    int cnt = min(64, N - n0);

    bf16x8 a8[8];
#pragma unroll
    for (int ni = 0; ni < 2; ++ni)
#pragma unroll
        for (int kk = 0; kk < 4; ++kk)
            a8[ni * 4 + kk] = *(const bf16x8*)(rwbt + ((w * 2 + ni) * 16 + lr) * NCH + kk * 32 + lg * 8);
    f32x4 bias[2];
#pragma unroll
    for (int ni = 0; ni < 2; ++ni) bias[ni] = *(const f32x4*)(rb + (w * 2 + ni) * 16 + lg * 4);

    const bf16x8 bz = {0, 0, 0, 0, 0, 0, 0, 0};
    if (row < cnt) {
        const bf16x8* xr = (const bf16x8*)(x_bf + (size_t)(n0 + row) * NCH);
#pragma unroll
        for (int jj = 0; jj < 4; ++jj)
            *(bf16x8*)(A + row * 256 + ((((jj << 2) + part) ^ (row & 7)) << 4)) = xr[jj * 4 + part];
    } else {
#pragma unroll
        for (int jj = 0; jj < 4; ++jj)
            *(bf16x8*)(A + row * 256 + ((((jj << 2) + part) ^ (row & 7)) << 4)) = bz;
    }
    __syncthreads();

    f32x4 acc[2][4];
#pragma unroll
    for (int ni = 0; ni < 2; ++ni)
#pragma unroll
        for (int et = 0; et < 4; ++et) acc[ni][et] = (f32x4){0.f, 0.f, 0.f, 0.f};
#pragma unroll
    for (int kk = 0; kk < 4; ++kk)
#pragma unroll
        for (int et = 0; et < 4; ++et) {
            int erow = et * 16 + lr;
            bf16x8 b = *(const bf16x8*)(A + erow * 256 + ((((kk << 2) + lg) ^ (erow & 7)) << 4));
            acc[0][et] = __builtin_amdgcn_mfma_f32_16x16x32_bf16(a8[0 + kk], b, acc[0][et], 0, 0, 0);
            acc[1][et] = __builtin_amdgcn_mfma_f32_16x16x32_bf16(a8[4 + kk], b, acc[1][et], 0, 0, 0);
        }

#pragma unroll
    for (int ni = 0; ni < 2; ++ni) {
        int oc0 = (w * 2 + ni) * 16 + lg * 4;
#pragma unroll
        for (int et = 0; et < 4; ++et) {
            int node = n0 + et * 16 + lr;
            if (node < N) {
                f32x4 v = acc[ni][et] + bias[ni];
                *(f32x4*)(out + (size_t)node * NCH + oc0) = v;
            }
        }
    }
}

static inline int imin(int a, int b) { return a < b ? a : b; }

extern "C" void kernel_launch(void* const* d_in, const int* in_sizes, int n_in,
                              void* d_out, int out_size, void* d_ws, size_t ws_size,
                              hipStream_t stream) {
    const float* x = (const float*)d_in[0];
    const int* trip = (const int*)d_in[1];
    const float* basis = (const float*)d_in[3];
    const float* att = (const float*)d_in[4];
    const float* rw = (const float*)d_in[5];
    const float* rb = (const float*)d_in[6];
    float* out = (float*)d_out;

    int N = in_sizes[0] / NCH;
    int E = in_sizes[1] / 3;

    char* ws = (char*)d_ws;
    size_t off = 0;
    auto alloc = [&](size_t b) { size_t o = off; off = (off + b + 255) & ~(size_t)255; return o; };
    size_t oWbt  = alloc((size_t)NREL * NCH * NCH * 2);  // 2 MB
    size_t oRwbt = alloc((size_t)NCH * NCH * 2);
    size_t oXbf  = alloc((size_t)N * NCH * 2);           // 25.6 MB
    size_t oDeg  = alloc((size_t)N * 4);                 // ---- memset zone start
    size_t oHist = alloc((MAXK + 1) * 4);
    size_t oKeyoff = alloc((MAXK + 1) * 4);              // ---- memset zone end
    size_t oBlkoff = alloc((MAXK + 1) * 4);
    size_t oCurK = alloc((MAXK + 1) * 4);
    size_t oBsum = alloc(1024 * 4);
    size_t oBoff = alloc(1024 * 4);
    size_t oDstoff = alloc(((size_t)N + 1) * 4);
    size_t oRank = alloc((size_t)E * 4);
    size_t oSrcs = alloc((size_t)E * 4);
    size_t oSlotOf = alloc((size_t)E * 4);
    size_t oMsgs = off;

    int C = MAXC;
    size_t cap = (size_t)E / MAXC + (size_t)E / (8 * MAXC) + 2048;
    const int opts[5] = {1, 2, 4, 8, 16};
    for (int i = 0; i < 5; ++i) {
        size_t ce = (opts[i] == 1) ? (size_t)E
                                   : ((size_t)E / opts[i] + (size_t)E / (8 * opts[i]) + 2048);
        if (oMsgs + ce * NCH * 2 <= ws_size) { C = opts[i]; cap = ce; break; }
    }
    int chunkNodes = (N + C - 1) / C;
    int NK = NREL * C;
    int blocksE = (E + ESB - 1) / ESB;
    int Bs = (N + 1023) / 1024;

    int* deg = (int*)(ws + oDeg);
    int* hist = (int*)(ws + oHist);
    int* keyoff = (int*)(ws + oKeyoff);
    int* blkoff = (int*)(ws + oBlkoff);
    int* curK = (int*)(ws + oCurK);
    int* bsum = (int*)(ws + oBsum);
    int* boff = (int*)(ws + oBoff);
    int* dstoff = (int*)(ws + oDstoff);
    int* rankOf = (int*)(ws + oRank);
    int* srcs = (int*)(ws + oSrcs);
    int* slotOf = (int*)(ws + oSlotOf);
    unsigned short* Wbt = (unsigned short*)(ws + oWbt);
    unsigned short* rwbt = (unsigned short*)(ws + oRwbt);
    unsigned short* x_bf = (unsigned short*)(ws + oXbf);
    unsigned short* msgs = (unsigned short*)(ws + oMsgs);

    hipMemsetAsync(ws + oDeg, 0, oKeyoff - oDeg, stream);  // deg, hist

    long total8 = (long)N * NCH / 8;
    k_prep<<<(int)((total8 + 255) / 256), 256, 0, stream>>>(x, x_bf, total8);
    k_buildW<<<NREL + 1, 256, 0, stream>>>(basis, att, rw, Wbt, rwbt);
    k_count<<<blocksE, 256, 0, stream>>>(trip, E, chunkNodes, NK, deg, hist, rankOf);
    k_scan_keys<<<1, 1024, 0, stream>>>(hist, NK, keyoff, blkoff, curK);
    k_scan_blk<<<Bs, 1024, 0, stream>>>(deg, N, dstoff, bsum);
    k_scan_top<<<1, 1024, 0, stream>>>(bsum, Bs, boff);
    k_scan_add<<<Bs, 1024, 0, stream>>>(dstoff, boff, N);
    k_scatter<<<blocksE, 256, 0, stream>>>(trip, E, chunkNodes, NK, dstoff, rankOf, curK, srcs, slotOf);

    k_rootmm<<<(N + 63) / 64, 256, 0, stream>>>(x_bf, rwbt, rb, out, N);

    int TB = (int)(cap / (64 * TSTRIP)) + NREL + 1;
    for (int c = 0; c < C; ++c) {
        k_msgs_mm<<<TB, 256, 0, stream>>>(x_bf, srcs, slotOf, Wbt, keyoff, blkoff, dstoff,
                                          msgs, c, chunkNodes, N);
        int lo = imin(c * chunkNodes, N);
        int hi = imin(lo + chunkNodes, N);
        if (hi > lo)
            k_agg<<<(hi - lo + 3) / 4, 256, 0, stream>>>(msgs, dstoff, out, lo, hi);
    }
}